// Round 2
// baseline (395.431 us; speedup 1.0000x reference)
//
#include <hip/hip_runtime.h>
#include <math.h>

#define L 4096
#define D 1024
#define H 16
#define KV 4
#define DH 64
// G = H/KV = 4

typedef __attribute__((ext_vector_type(8))) short bf16x8;
typedef __attribute__((ext_vector_type(4))) float f32x4;
typedef __attribute__((ext_vector_type(16))) float f32x16;
typedef __attribute__((ext_vector_type(2))) unsigned int u32x2;

static __device__ __forceinline__ unsigned short f2bf(float f) {
    unsigned u = __float_as_uint(f);
    u = (u + 0x7FFF + ((u >> 16) & 1)) >> 16;   // RNE
    return (unsigned short)u;
}

static __device__ __forceinline__ bf16x8 mk8(unsigned a, unsigned b, unsigned c, unsigned d) {
    union { unsigned u[4]; bf16x8 v; } x;
    x.u[0] = a; x.u[1] = b; x.u[2] = c; x.u[3] = d;
    return x.v;
}

#define EXP2F(x) __builtin_amdgcn_exp2f(x)
#define ZERO16 ((f32x16){0.f,0.f,0.f,0.f,0.f,0.f,0.f,0.f,0.f,0.f,0.f,0.f,0.f,0.f,0.f,0.f})

// async global->LDS, 16B per lane; dst must be wave-uniform base (HW: base + lane*16)
#define GLD16(src, dst) \
    __builtin_amdgcn_global_load_lds((__attribute__((address_space(1))) void*)(src), \
                                     (__attribute__((address_space(3))) void*)(dst), 16, 0, 0)

// ---------------------------------------------------------------------------
// prep: x fp32->bf16, and the four weight transposes (dst[n][k] bf16, K=1024).
// ---------------------------------------------------------------------------
__global__ __launch_bounds__(256) void prep_kernel(
        const float* __restrict__ x,  const float* __restrict__ Wq,
        const float* __restrict__ Wk, const float* __restrict__ Wv,
        const float* __restrict__ Wo,
        unsigned short* __restrict__ xb, unsigned short* __restrict__ WqkvT,
        unsigned short* __restrict__ WoT) {
    const int b = blockIdx.x, tid = threadIdx.x;
    if (b < 4096) {
        int i = (b * 256 + tid) * 4;
        float4 v = *(const float4*)&x[i];
        ushort4 o;
        o.x = f2bf(v.x); o.y = f2bf(v.y); o.z = f2bf(v.z); o.w = f2bf(v.w);
        *(ushort4*)&xb[i] = o;
        return;
    }
    __shared__ float t[32][33];
    const float* src; unsigned short* dst; int N, n0, k0;
    if (b < 5120)      { int tq = b - 4096; src = Wq; dst = WqkvT;                     N = 1024; n0 = (tq & 31) * 32; k0 = (tq >> 5) * 32; }
    else if (b < 5376) { int tq = b - 5120; src = Wk; dst = WqkvT + (size_t)1024*1024; N = 256;  n0 = (tq & 7)  * 32; k0 = (tq >> 3) * 32; }
    else if (b < 5632) { int tq = b - 5376; src = Wv; dst = WqkvT + (size_t)1280*1024; N = 256;  n0 = (tq & 7)  * 32; k0 = (tq >> 3) * 32; }
    else               { int tq = b - 5632; src = Wo; dst = WoT;                       N = 1024; n0 = (tq & 31) * 32; k0 = (tq >> 5) * 32; }
    const int tx = tid & 31, ty = tid >> 5;
    #pragma unroll
    for (int j = 0; j < 4; ++j)
        t[ty + 8 * j][tx] = src[(size_t)(k0 + ty + 8 * j) * N + n0 + tx];
    __syncthreads();
    #pragma unroll
    for (int j = 0; j < 4; ++j)
        dst[(size_t)(n0 + ty + 8 * j) * 1024 + k0 + tx] = f2bf(t[tx][ty + 8 * j]);
}

// ---------------------------------------------------------------------------
// bf16 MFMA GEMM (fp32 out) for the Wo projection.
// ---------------------------------------------------------------------------
__global__ __launch_bounds__(256) void gemm_bf16(const unsigned short* __restrict__ A,
                                                 const unsigned short* __restrict__ BT,
                                                 float* __restrict__ C,
                                                 int M, int N, int K) {
    __shared__ unsigned short As[128 * 32];
    __shared__ unsigned short Bs[128 * 32];

    const int tid  = threadIdx.x;
    const int w    = tid >> 6;
    const int lane = tid & 63;
    const int c    = lane & 15;
    const int quad = lane >> 4;
    const int wy = w >> 1, wx = w & 1;
    const int row0 = blockIdx.y * 128;
    const int col0 = blockIdx.x * 128;

    const int ld_row = w * 16 + (lane >> 2);
    const int ld_col = (lane & 3) * 8;

    f32x4 acc[4][4];
    #pragma unroll
    for (int mt = 0; mt < 4; ++mt)
        #pragma unroll
        for (int nt = 0; nt < 4; ++nt)
            acc[mt][nt] = (f32x4){0.f, 0.f, 0.f, 0.f};

    for (int k0 = 0; k0 < K; k0 += 32) {
        __syncthreads();
        GLD16(&A [(size_t)(row0 + ld_row)      * K + k0 + ld_col], &As[w * 512]);
        GLD16(&A [(size_t)(row0 + ld_row + 64) * K + k0 + ld_col], &As[w * 512 + 2048]);
        GLD16(&BT[(size_t)(col0 + ld_row)      * K + k0 + ld_col], &Bs[w * 512]);
        GLD16(&BT[(size_t)(col0 + ld_row + 64) * K + k0 + ld_col], &Bs[w * 512 + 2048]);
        __syncthreads();

        bf16x8 af[4], bfr[4];
        #pragma unroll
        for (int mt = 0; mt < 4; ++mt)
            af[mt] = *(const bf16x8*)&As[(wy * 64 + mt * 16 + c) * 32 + quad * 8];
        #pragma unroll
        for (int nt = 0; nt < 4; ++nt)
            bfr[nt] = *(const bf16x8*)&Bs[(wx * 64 + nt * 16 + c) * 32 + quad * 8];

        #pragma unroll
        for (int mt = 0; mt < 4; ++mt)
            #pragma unroll
            for (int nt = 0; nt < 4; ++nt)
                acc[mt][nt] = __builtin_amdgcn_mfma_f32_16x16x32_bf16(af[mt], bfr[nt], acc[mt][nt], 0, 0, 0);
    }

    #pragma unroll
    for (int mt = 0; mt < 4; ++mt)
        #pragma unroll
        for (int nt = 0; nt < 4; ++nt)
            #pragma unroll
            for (int r = 0; r < 4; ++r)
                C[(size_t)(row0 + wy * 64 + mt * 16 + quad * 4 + r) * N
                  + col0 + wx * 64 + nt * 16 + c] = acc[mt][nt][r];
}

// ---------------------------------------------------------------------------
// Fused QKV GEMM + RoPE epilogue. (unchanged)
// ---------------------------------------------------------------------------
__global__ __launch_bounds__(256) void gemm_qkv_rope(
        const unsigned short* __restrict__ A,
        const unsigned short* __restrict__ BT,
        unsigned short* __restrict__ qb,
        unsigned short* __restrict__ kbuf,
        unsigned short* __restrict__ vbuf) {
    __shared__ unsigned short As[128 * 32];
    __shared__ unsigned short Bs[128 * 32];

    const int tid  = threadIdx.x;
    const int w    = tid >> 6;
    const int lane = tid & 63;
    const int c    = lane & 15;
    const int quad = lane >> 4;
    const int wy = w >> 1, wx = w & 1;
    const int row0 = blockIdx.y * 128;
    const int col0 = blockIdx.x * 128;

    const int ld_row = w * 16 + (lane >> 2);
    const int ld_col = (lane & 3) * 8;

    f32x4 acc[4][4];
    #pragma unroll
    for (int mt = 0; mt < 4; ++mt)
        #pragma unroll
        for (int nt = 0; nt < 4; ++nt)
            acc[mt][nt] = (f32x4){0.f, 0.f, 0.f, 0.f};

    for (int k0 = 0; k0 < 1024; k0 += 32) {
        __syncthreads();
        GLD16(&A [(size_t)(row0 + ld_row)      * 1024 + k0 + ld_col], &As[w * 512]);
        GLD16(&A [(size_t)(row0 + ld_row + 64) * 1024 + k0 + ld_col], &As[w * 512 + 2048]);
        GLD16(&BT[(size_t)(col0 + ld_row)      * 1024 + k0 + ld_col], &Bs[w * 512]);
        GLD16(&BT[(size_t)(col0 + ld_row + 64) * 1024 + k0 + ld_col], &Bs[w * 512 + 2048]);
        __syncthreads();

        bf16x8 af[4], bfr[4];
        #pragma unroll
        for (int mt = 0; mt < 4; ++mt)
            af[mt] = *(const bf16x8*)&As[(wy * 64 + mt * 16 + c) * 32 + quad * 8];
        #pragma unroll
        for (int nt = 0; nt < 4; ++nt)
            bfr[nt] = *(const bf16x8*)&Bs[(wx * 64 + nt * 16 + c) * 32 + quad * 8];

        #pragma unroll
        for (int mt = 0; mt < 4; ++mt)
            #pragma unroll
            for (int nt = 0; nt < 4; ++nt)
                acc[mt][nt] = __builtin_amdgcn_mfma_f32_16x16x32_bf16(af[mt], bfr[nt], acc[mt][nt], 0, 0, 0);
    }

    const int colb = col0 + wx * 64;
    if (colb < 1280) {
        unsigned short* dst; int hh, hstride; float scale;
        if (colb < 1024) { dst = qb;   hh = colb >> 6;          hstride = H;  scale = 0.18033688011112042f; }
        else             { dst = kbuf; hh = (colb - 1024) >> 6; hstride = KV; scale = 1.0f; }
        #pragma unroll
        for (int nt = 0; nt < 2; ++nt) {
            int d = nt * 16 + c;
            float invf = EXP2F((float)d * -0.4152410118609203f);
            #pragma unroll
            for (int mt = 0; mt < 4; ++mt)
                #pragma unroll
                for (int r = 0; r < 4; ++r) {
                    int l = row0 + wy * 64 + mt * 16 + quad * 4 + r;
                    float ang = (float)l * invf;
                    float sn = __sinf(ang), cs = __cosf(ang);
                    float x1 = acc[mt][nt][r], x2 = acc[mt][nt + 2][r];
                    dst[((size_t)l * hstride + hh) * DH + d]      = f2bf((x1 * cs - x2 * sn) * scale);
                    dst[((size_t)l * hstride + hh) * DH + d + 32] = f2bf((x2 * cs + x1 * sn) * scale);
                }
        }
    } else {
        int vh = (colb - 1280) >> 6;
        #pragma unroll
        for (int mt = 0; mt < 4; ++mt)
            #pragma unroll
            for (int nt = 0; nt < 4; ++nt)
                #pragma unroll
                for (int r = 0; r < 4; ++r) {
                    int l = row0 + wy * 64 + mt * 16 + quad * 4 + r;
                    vbuf[((size_t)l * KV + vh) * DH + nt * 16 + c] = f2bf(acc[mt][nt][r]);
                }
    }
}

// ---------------------------------------------------------------------------
// MFMA attention, 32x32x16 shape, key-split-in-block. Grid (64, KV), 512 thr.
// Wave w: head kv*4+(w&3), key-half g=w>>2 (2048 keys, 32 iters of 64),
// 64 q-rows per wave. Per iter: 16 St MFMA + 16 PV MFMA (32x32x16).
// P never touches LDS: after St (D: col=q=lane&31, row=key=(r&3)+8(r>>2)+4hi),
// exp2 -> bf16-truncate -> byte-perm pack -> permlane32_swap builds the PV
// A-frags (row=q=lane&31, k=key=hi*8+j) entirely in registers. Rowsums are
// VALU adds on the truncated values (matches bf16 PV numerator domain),
// combined across hi-halves once at the end (no ones-MFMA).
// K direct global->regs (single buffer, prefetched mid-iter). V staged
// per-group to swizzled LDS (double-buffered). One barrier/iter.
// Epilogue: group 1 dumps fp32 partials (swizzled [d][q] LDS); group 0 adds,
// normalizes with Rs rowsums, stores (partial softmax sums are additive).
//
// __launch_bounds__(512, 1): the working set is ~210 VGPRs. With (512, 2)
// the allocator was capped at 128 VGPRs and spilled ~400 MB/dispatch of
// scratch each way (R1 counters: WRITE_SIZE 428 MB, MfmaUtil 10%).
// Occupancy is structurally 1 block/CU anyway (grid=256, LDS=100 KB), so
// the full 256-VGPR budget at 2 waves/SIMD is free.
// ---------------------------------------------------------------------------
__global__ __launch_bounds__(512, 1) void attn_mfma_kernel(
        const unsigned short* __restrict__ qb,
        const unsigned short* __restrict__ kb,
        const unsigned short* __restrict__ vb,
        unsigned short* __restrict__ ob) {
    __shared__ __align__(16) unsigned short Vt[2][2][64][64];  // 32 KB [group][buf][d][key]
    __shared__ __align__(16) float Ep[4][64][64];              // 64 KB epilogue fp32 partials
    __shared__ __align__(16) float Rs[8][2][32];               //  2 KB rowsums [wave][qt][q]

    const int tid  = threadIdx.x;
    const int w    = tid >> 6;        // 0..7
    const int lane = tid & 63;
    const int c32  = lane & 31;
    const int hi   = lane >> 5;
    const int g    = w >> 2;          // key group
    const int kv = blockIdx.y;
    const int h  = kv * 4 + (w & 3);
    const int q0 = blockIdx.x * 64;
    const int s_base = g * 2048;

    // Q B-frags: col=q=c32, k-elems d = kd*16 + hi*8 + j
    bf16x8 qf[2][4];
    {
        const unsigned short* qbase = qb + ((size_t)(q0 + c32) * H + h) * DH + hi * 8;
        #pragma unroll
        for (int qt = 0; qt < 2; ++qt)
            #pragma unroll
            for (int kd = 0; kd < 4; ++kd)
                qf[qt][kd] = *(const bf16x8*)&qbase[qt * 32 * H * DH + kd * 16];
    }

    f32x16 oacc[2][2];    // [qt][dt]: col=d=c32(+32dt), row=q=(r&3)+8(r>>2)+4hi
    #pragma unroll
    for (int qt = 0; qt < 2; ++qt)
        #pragma unroll
        for (int dt = 0; dt < 2; ++dt)
            oacc[qt][dt] = ZERO16;
    float rsum[2] = {0.f, 0.f};   // per-lane partial rowsum, q = qt*32 + c32

    const int tid8 = tid & 255;                 // id within group
    const int sp = tid8 & 31, dc = tid8 >> 5;   // V staging: keys (2sp,2sp+1), d-chunk dc*8

    const unsigned short* kbase = kb + ((size_t)(s_base + c32) * KV + kv) * DH + hi * 8;
    const unsigned short* vbase = vb + ((size_t)(s_base + 2 * sp) * KV + kv) * DH + dc * 8;

    // ---- prefetch iter 0 ----
    int4 vreg0 = *(const int4*)&vbase[0];
    int4 vreg1 = *(const int4*)&vbase[KV * DH];
    bf16x8 kf[2][4];   // [key-32-tile][kd]: row=key=c32, k-elems d = kd*16+hi*8+j
    #pragma unroll
    for (int a = 0; a < 2; ++a)
        #pragma unroll
        for (int kd = 0; kd < 4; ++kd)
            kf[a][kd] = *(const bf16x8*)&kbase[a * 32 * KV * DH + kd * 16];

    auto step = [&](int it, int buf) {
        // ---- write Vt[g][buf] (pair-transpose via perm, swizzled) ----
        {
            const unsigned* pa = (const unsigned*)&vreg0;
            const unsigned* pb = (const unsigned*)&vreg1;
            #pragma unroll
            for (int t = 0; t < 4; ++t) {
                unsigned lo = __builtin_amdgcn_perm(pb[t], pa[t], 0x05040100u);
                unsigned hv = __builtin_amdgcn_perm(pb[t], pa[t], 0x07060302u);
                int dl = dc * 8 + 2 * t, dh2 = dl + 1;
                *(unsigned*)&Vt[g][buf][dl ][(((sp >> 2) ^ (dl  & 7)) << 3) + 2 * (sp & 3)] = lo;
                *(unsigned*)&Vt[g][buf][dh2][(((sp >> 2) ^ (dh2 & 7)) << 3) + 2 * (sp & 3)] = hv;
            }
        }
        __syncthreads();   // Vt[g][buf] visible; prior-iter reads complete

        // ---- V prefetch next (overlaps compute) ----
        const int itn = (it + 1) & 31;
        vreg0 = *(const int4*)&vbase[(size_t)itn * 64 * KV * DH];
        vreg1 = *(const int4*)&vbase[(size_t)itn * 64 * KV * DH + KV * DH];

        #pragma unroll
        for (int kt2 = 0; kt2 < 2; ++kt2) {
            bf16x8 pf[2][2];   // [qt][f]: PV A-frags, keys kt2*32 + f*16 + hi*8 + j
            #pragma unroll
            for (int qt = 0; qt < 2; ++qt) {
                // St = K @ Q^T (32x32, K-dim = DH via 4 chained MFMAs)
                f32x16 s = ZERO16;
                #pragma unroll
                for (int kd = 0; kd < 4; ++kd)
                    s = __builtin_amdgcn_mfma_f32_32x32x16_bf16(kf[kt2][kd], qf[qt][kd], s, 0, 0, 0);
                // exp2, truncate to bf16 domain (matches packed PV operand)
                float p[16];
                #pragma unroll
                for (int r = 0; r < 16; ++r)
                    p[r] = __uint_as_float(__float_as_uint(EXP2F(s[r])) & 0xFFFF0000u);
                // rowsum for q = qt*32+c32 over this lane's 16 keys
                float t0 = (p[0] + p[1]) + (p[2] + p[3]);
                float t1 = (p[4] + p[5]) + (p[6] + p[7]);
                float t2 = (p[8] + p[9]) + (p[10] + p[11]);
                float t3 = (p[12] + p[13]) + (p[14] + p[15]);
                rsum[qt] += (t0 + t1) + (t2 + t3);
                // pack key-pairs: u[i] = bf16(p[2i]) | bf16(p[2i+1])<<16
                unsigned u[8];
                #pragma unroll
                for (int i = 0; i < 8; ++i)
                    u[i] = __builtin_amdgcn_perm(__float_as_uint(p[2 * i + 1]),
                                                 __float_as_uint(p[2 * i]), 0x07060302u);
                // cross-half redistribute: u regs hold keys {0,1}{2,3}{8,9}{10,11}
                // (+4hi) per 16-key frag; swap(u0,u2)->slots{0,2}, swap(u1,u3)->slots{1,3}
                #pragma unroll
                for (int f = 0; f < 2; ++f) {
                    u32x2 e0 = __builtin_amdgcn_permlane32_swap(u[4 * f + 0], u[4 * f + 2], false, false);
                    u32x2 e1 = __builtin_amdgcn_permlane32_swap(u[4 * f + 1], u[4 * f + 3], false, false);
                    pf[qt][f] = mk8(e0.x, e1.x, e0.y, e1.y);
                }
            }
            if (kt2 == 1) {
                // K prefetch next iter (after last St read of kf)
                #pragma unroll
                for (int a = 0; a < 2; ++a)
                    #pragma unroll
                    for (int kd = 0; kd < 4; ++kd)
                        kf[a][kd] = *(const bf16x8*)&kbase[((size_t)itn * 64 + a * 32) * KV * DH + kd * 16];
            }
            // ---- PV half-tile: O += P @ V over keys kt2*32..+31 ----
            __builtin_amdgcn_s_setprio(1);
            #pragma unroll
            for (int dt = 0; dt < 2; ++dt)
                #pragma unroll
                for (int f = 0; f < 2; ++f) {
                    bf16x8 vf = *(const bf16x8*)&Vt[g][buf][dt * 32 + c32]
                                    [(((kt2 * 4 + f * 2 + hi) ^ (c32 & 7)) << 3)];
                    #pragma unroll
                    for (int qt = 0; qt < 2; ++qt)
                        oacc[qt][dt] = __builtin_amdgcn_mfma_f32_32x32x16_bf16(pf[qt][f], vf, oacc[qt][dt], 0, 0, 0);
                }
            __builtin_amdgcn_s_setprio(0);
        }
    };

    for (int it = 0; it < 32; it += 2) {
        step(it,     0);
        step(it + 1, 1);
    }

    // ---- epilogue: combine hi-halves of rowsums, then key-halves ----
    #pragma unroll
    for (int qt = 0; qt < 2; ++qt) {
        u32x2 e = __builtin_amdgcn_permlane32_swap(__float_as_uint(rsum[qt]),
                                                   __float_as_uint(rsum[qt]), false, false);
        float tot = __uint_as_float(e.x) + __uint_as_float(e.y);
        Rs[w][qt][c32] = tot;   // both hi-lanes write identical value (benign)
    }
    if (g == 1) {
        #pragma unroll
        for (int qt = 0; qt < 2; ++qt)
            #pragma unroll
            for (int dt = 0; dt < 2; ++dt) {
                const int d = dt * 32 + c32;
                #pragma unroll
                for (int rr = 0; rr < 4; ++rr) {
                    const int gq = (qt * 8 + 2 * rr + hi) ^ (d & 15);   // 16B-granule swizzle
                    f32x4 val = {oacc[qt][dt][rr * 4 + 0], oacc[qt][dt][rr * 4 + 1],
                                 oacc[qt][dt][rr * 4 + 2], oacc[qt][dt][rr * 4 + 3]};
                    *(f32x4*)&Ep[w - 4][d][gq * 4] = val;
                }
            }
    }
    __syncthreads();
    if (g == 0) {
        #pragma unroll
        for (int qt = 0; qt < 2; ++qt)
            #pragma unroll
            for (int dt = 0; dt < 2; ++dt) {
                const int d = dt * 32 + c32;
                #pragma unroll
                for (int rr = 0; rr < 4; ++rr) {
                    const int gq = (qt * 8 + 2 * rr + hi) ^ (d & 15);
                    f32x4 val = *(const f32x4*)&Ep[w][d][gq * 4];
                    oacc[qt][dt][rr * 4 + 0] += val[0];
                    oacc[qt][dt][rr * 4 + 1] += val[1];
                    oacc[qt][dt][rr * 4 + 2] += val[2];
                    oacc[qt][dt][rr * 4 + 3] += val[3];
                }
            }
        #pragma unroll
        for (int qt = 0; qt < 2; ++qt)
            #pragma unroll
            for (int rr = 0; rr < 4; ++rr) {
                f32x4 ra = *(const f32x4*)&Rs[w][qt][8 * rr + 4 * hi];
                f32x4 rb = *(const f32x4*)&Rs[w + 4][qt][8 * rr + 4 * hi];
                #pragma unroll
                for (int i = 0; i < 4; ++i) {
                    float inv = 1.0f / (ra[i] + rb[i]);
                    int row = q0 + qt * 32 + 8 * rr + 4 * hi + i;
                    #pragma unroll
                    for (int dt = 0; dt < 2; ++dt)
                        ob[(size_t)row * (H * DH) + h * DH + dt * 32 + c32] =
                            f2bf(oacc[qt][dt][rr * 4 + i] * inv);
                }
            }
    }
}

// ---------------------------------------------------------------------------
extern "C" void kernel_launch(void* const* d_in, const int* in_sizes, int n_in,
                              void* d_out, int out_size, void* d_ws, size_t ws_size,
                              hipStream_t stream) {
    const float* x  = (const float*)d_in[0];
    const float* Wq = (const float*)d_in[1];
    const float* Wk = (const float*)d_in[2];
    const float* Wv = (const float*)d_in[3];
    const float* Wo = (const float*)d_in[4];
    float* out = (float*)d_out;

    // ---- workspace (~26.2 MB) ----
    char* ws = (char*)d_ws;
    unsigned short* xb    = (unsigned short*)ws;                      // 8.39 MB
    unsigned short* ob    = xb;                                       // aliases xb (dead after QKV GEMM)
    unsigned short* qb    = (unsigned short*)(ws + 8388608);          // 8.39 MB
    unsigned short* kb    = (unsigned short*)(ws + 16777216);         // 2.10 MB
    unsigned short* vb    = (unsigned short*)(ws + 18874368);         // 2.10 MB
    unsigned short* WqkvT = (unsigned short*)(ws + 20971520);         // 3.15 MB
    unsigned short* WoT   = (unsigned short*)(ws + 24117248);         // 2.10 MB

    dim3 blk(256);

    // 1) convert + transpose everything
    prep_kernel<<<6656, blk, 0, stream>>>(x, Wq, Wk, Wv, Wo, xb, WqkvT, WoT);

    // 2) fused QKV projection + RoPE + bf16 pack
    gemm_qkv_rope<<<dim3(12, 32), blk, 0, stream>>>(xb, WqkvT, qb, kb, vb);

    // 3) attention (writes bf16 ob over xb — dead)
    attn_mfma_kernel<<<dim3(L / 64, KV), dim3(512), 0, stream>>>(qb, kb, vb, ob);

    // 4) output projection
    gemm_bf16<<<dim3(D / 128, L / 128), blk, 0, stream>>>(ob, WoT, out, L, D, D);
}

// Round 3
// 213.581 us; speedup vs baseline: 1.8514x; 1.8514x over previous
//
#include <hip/hip_runtime.h>
#include <math.h>

#define L 4096
#define D 1024
#define H 16
#define KV 4
#define DH 64
// G = H/KV = 4

typedef __attribute__((ext_vector_type(8))) short bf16x8;
typedef __attribute__((ext_vector_type(4))) float f32x4;
typedef __attribute__((ext_vector_type(16))) float f32x16;
typedef __attribute__((ext_vector_type(2))) unsigned int u32x2;

static __device__ __forceinline__ unsigned short f2bf(float f) {
    unsigned u = __float_as_uint(f);
    u = (u + 0x7FFF + ((u >> 16) & 1)) >> 16;   // RNE
    return (unsigned short)u;
}

static __device__ __forceinline__ bf16x8 mk8(unsigned a, unsigned b, unsigned c, unsigned d) {
    union { unsigned u[4]; bf16x8 v; } x;
    x.u[0] = a; x.u[1] = b; x.u[2] = c; x.u[3] = d;
    return x.v;
}

#define EXP2F(x) __builtin_amdgcn_exp2f(x)
#define ZERO16 ((f32x16){0.f,0.f,0.f,0.f,0.f,0.f,0.f,0.f,0.f,0.f,0.f,0.f,0.f,0.f,0.f,0.f})

// async global->LDS, 16B per lane; dst must be wave-uniform base (HW: base + lane*16)
#define GLD16(src, dst) \
    __builtin_amdgcn_global_load_lds((__attribute__((address_space(1))) void*)(src), \
                                     (__attribute__((address_space(3))) void*)(dst), 16, 0, 0)

// ---------------------------------------------------------------------------
// prep: x fp32->bf16, and the four weight transposes (dst[n][k] bf16, K=1024).
// ---------------------------------------------------------------------------
__global__ __launch_bounds__(256) void prep_kernel(
        const float* __restrict__ x,  const float* __restrict__ Wq,
        const float* __restrict__ Wk, const float* __restrict__ Wv,
        const float* __restrict__ Wo,
        unsigned short* __restrict__ xb, unsigned short* __restrict__ WqkvT,
        unsigned short* __restrict__ WoT) {
    const int b = blockIdx.x, tid = threadIdx.x;
    if (b < 4096) {
        int i = (b * 256 + tid) * 4;
        float4 v = *(const float4*)&x[i];
        ushort4 o;
        o.x = f2bf(v.x); o.y = f2bf(v.y); o.z = f2bf(v.z); o.w = f2bf(v.w);
        *(ushort4*)&xb[i] = o;
        return;
    }
    __shared__ float t[32][33];
    const float* src; unsigned short* dst; int N, n0, k0;
    if (b < 5120)      { int tq = b - 4096; src = Wq; dst = WqkvT;                     N = 1024; n0 = (tq & 31) * 32; k0 = (tq >> 5) * 32; }
    else if (b < 5376) { int tq = b - 5120; src = Wk; dst = WqkvT + (size_t)1024*1024; N = 256;  n0 = (tq & 7)  * 32; k0 = (tq >> 3) * 32; }
    else if (b < 5632) { int tq = b - 5376; src = Wv; dst = WqkvT + (size_t)1280*1024; N = 256;  n0 = (tq & 7)  * 32; k0 = (tq >> 3) * 32; }
    else               { int tq = b - 5632; src = Wo; dst = WoT;                       N = 1024; n0 = (tq & 31) * 32; k0 = (tq >> 5) * 32; }
    const int tx = tid & 31, ty = tid >> 5;
    #pragma unroll
    for (int j = 0; j < 4; ++j)
        t[ty + 8 * j][tx] = src[(size_t)(k0 + ty + 8 * j) * N + n0 + tx];
    __syncthreads();
    #pragma unroll
    for (int j = 0; j < 4; ++j)
        dst[(size_t)(n0 + ty + 8 * j) * 1024 + k0 + tx] = f2bf(t[tx][ty + 8 * j]);
}

// ---------------------------------------------------------------------------
// bf16 MFMA GEMM (fp32 out) for the Wo projection.
// ---------------------------------------------------------------------------
__global__ __launch_bounds__(256) void gemm_bf16(const unsigned short* __restrict__ A,
                                                 const unsigned short* __restrict__ BT,
                                                 float* __restrict__ C,
                                                 int M, int N, int K) {
    __shared__ unsigned short As[128 * 32];
    __shared__ unsigned short Bs[128 * 32];

    const int tid  = threadIdx.x;
    const int w    = tid >> 6;
    const int lane = tid & 63;
    const int c    = lane & 15;
    const int quad = lane >> 4;
    const int wy = w >> 1, wx = w & 1;
    const int row0 = blockIdx.y * 128;
    const int col0 = blockIdx.x * 128;

    const int ld_row = w * 16 + (lane >> 2);
    const int ld_col = (lane & 3) * 8;

    f32x4 acc[4][4];
    #pragma unroll
    for (int mt = 0; mt < 4; ++mt)
        #pragma unroll
        for (int nt = 0; nt < 4; ++nt)
            acc[mt][nt] = (f32x4){0.f, 0.f, 0.f, 0.f};

    for (int k0 = 0; k0 < K; k0 += 32) {
        __syncthreads();
        GLD16(&A [(size_t)(row0 + ld_row)      * K + k0 + ld_col], &As[w * 512]);
        GLD16(&A [(size_t)(row0 + ld_row + 64) * K + k0 + ld_col], &As[w * 512 + 2048]);
        GLD16(&BT[(size_t)(col0 + ld_row)      * K + k0 + ld_col], &Bs[w * 512]);
        GLD16(&BT[(size_t)(col0 + ld_row + 64) * K + k0 + ld_col], &Bs[w * 512 + 2048]);
        __syncthreads();

        bf16x8 af[4], bfr[4];
        #pragma unroll
        for (int mt = 0; mt < 4; ++mt)
            af[mt] = *(const bf16x8*)&As[(wy * 64 + mt * 16 + c) * 32 + quad * 8];
        #pragma unroll
        for (int nt = 0; nt < 4; ++nt)
            bfr[nt] = *(const bf16x8*)&Bs[(wx * 64 + nt * 16 + c) * 32 + quad * 8];

        #pragma unroll
        for (int mt = 0; mt < 4; ++mt)
            #pragma unroll
            for (int nt = 0; nt < 4; ++nt)
                acc[mt][nt] = __builtin_amdgcn_mfma_f32_16x16x32_bf16(af[mt], bfr[nt], acc[mt][nt], 0, 0, 0);
    }

    #pragma unroll
    for (int mt = 0; mt < 4; ++mt)
        #pragma unroll
        for (int nt = 0; nt < 4; ++nt)
            #pragma unroll
            for (int r = 0; r < 4; ++r)
                C[(size_t)(row0 + wy * 64 + mt * 16 + quad * 4 + r) * N
                  + col0 + wx * 64 + nt * 16 + c] = acc[mt][nt][r];
}

// ---------------------------------------------------------------------------
// Fused QKV GEMM + RoPE epilogue. (unchanged)
// ---------------------------------------------------------------------------
__global__ __launch_bounds__(256) void gemm_qkv_rope(
        const unsigned short* __restrict__ A,
        const unsigned short* __restrict__ BT,
        unsigned short* __restrict__ qb,
        unsigned short* __restrict__ kbuf,
        unsigned short* __restrict__ vbuf) {
    __shared__ unsigned short As[128 * 32];
    __shared__ unsigned short Bs[128 * 32];

    const int tid  = threadIdx.x;
    const int w    = tid >> 6;
    const int lane = tid & 63;
    const int c    = lane & 15;
    const int quad = lane >> 4;
    const int wy = w >> 1, wx = w & 1;
    const int row0 = blockIdx.y * 128;
    const int col0 = blockIdx.x * 128;

    const int ld_row = w * 16 + (lane >> 2);
    const int ld_col = (lane & 3) * 8;

    f32x4 acc[4][4];
    #pragma unroll
    for (int mt = 0; mt < 4; ++mt)
        #pragma unroll
        for (int nt = 0; nt < 4; ++nt)
            acc[mt][nt] = (f32x4){0.f, 0.f, 0.f, 0.f};

    for (int k0 = 0; k0 < 1024; k0 += 32) {
        __syncthreads();
        GLD16(&A [(size_t)(row0 + ld_row)      * 1024 + k0 + ld_col], &As[w * 512]);
        GLD16(&A [(size_t)(row0 + ld_row + 64) * 1024 + k0 + ld_col], &As[w * 512 + 2048]);
        GLD16(&BT[(size_t)(col0 + ld_row)      * 1024 + k0 + ld_col], &Bs[w * 512]);
        GLD16(&BT[(size_t)(col0 + ld_row + 64) * 1024 + k0 + ld_col], &Bs[w * 512 + 2048]);
        __syncthreads();

        bf16x8 af[4], bfr[4];
        #pragma unroll
        for (int mt = 0; mt < 4; ++mt)
            af[mt] = *(const bf16x8*)&As[(wy * 64 + mt * 16 + c) * 32 + quad * 8];
        #pragma unroll
        for (int nt = 0; nt < 4; ++nt)
            bfr[nt] = *(const bf16x8*)&Bs[(wx * 64 + nt * 16 + c) * 32 + quad * 8];

        #pragma unroll
        for (int mt = 0; mt < 4; ++mt)
            #pragma unroll
            for (int nt = 0; nt < 4; ++nt)
                acc[mt][nt] = __builtin_amdgcn_mfma_f32_16x16x32_bf16(af[mt], bfr[nt], acc[mt][nt], 0, 0, 0);
    }

    const int colb = col0 + wx * 64;
    if (colb < 1280) {
        unsigned short* dst; int hh, hstride; float scale;
        if (colb < 1024) { dst = qb;   hh = colb >> 6;          hstride = H;  scale = 0.18033688011112042f; }
        else             { dst = kbuf; hh = (colb - 1024) >> 6; hstride = KV; scale = 1.0f; }
        #pragma unroll
        for (int nt = 0; nt < 2; ++nt) {
            int d = nt * 16 + c;
            float invf = EXP2F((float)d * -0.4152410118609203f);
            #pragma unroll
            for (int mt = 0; mt < 4; ++mt)
                #pragma unroll
                for (int r = 0; r < 4; ++r) {
                    int l = row0 + wy * 64 + mt * 16 + quad * 4 + r;
                    float ang = (float)l * invf;
                    float sn = __sinf(ang), cs = __cosf(ang);
                    float x1 = acc[mt][nt][r], x2 = acc[mt][nt + 2][r];
                    dst[((size_t)l * hstride + hh) * DH + d]      = f2bf((x1 * cs - x2 * sn) * scale);
                    dst[((size_t)l * hstride + hh) * DH + d + 32] = f2bf((x2 * cs + x1 * sn) * scale);
                }
        }
    } else {
        int vh = (colb - 1280) >> 6;
        #pragma unroll
        for (int mt = 0; mt < 4; ++mt)
            #pragma unroll
            for (int nt = 0; nt < 4; ++nt)
                #pragma unroll
                for (int r = 0; r < 4; ++r) {
                    int l = row0 + wy * 64 + mt * 16 + quad * 4 + r;
                    vbuf[((size_t)l * KV + vh) * DH + nt * 16 + c] = f2bf(acc[mt][nt][r]);
                }
    }
}

// ---------------------------------------------------------------------------
// MFMA attention, 32x32x16 shape, key-split-in-block. Grid (64, KV), 512 thr.
// Wave w: head kv*4+(w&3), key-half g=w>>2 (2048 keys, 32 iters of 64),
// 64 q-rows per wave. Per iter: 16 St MFMA + 16 PV MFMA (32x32x16).
// P never touches LDS: after St (D: col=q=lane&31, row=key=(r&3)+8(r>>2)+4hi),
// exp2 -> bf16-truncate -> byte-perm pack -> permlane32_swap builds the PV
// A-frags (row=q=lane&31, k=key=hi*8+j) entirely in registers. Rowsums are
// VALU adds on the truncated values, combined across hi-halves at the end.
// K direct global->regs (prefetched mid-iter). V staged per-group to
// swizzled LDS (double-buffered, runtime buf = it&1 -> LDS addressing only).
// One barrier/iter. Epilogue: group 1 dumps fp32 partials; group 0 adds,
// normalizes with Rs rowsums, stores (partial softmax sums are additive).
//
// NOTE (R2 post-mortem): the main loop body MUST be a plain loop body, not a
// [&]-capturing lambda. The un-inlined closure forced all captured register
// arrays (oacc/qf/kf/vreg) to scratch: 428 MB WRITE_SIZE, MfmaUtil 10%.
// amdgpu_waves_per_eu(2) guarantees the 8-wave block remains launchable
// (2 waves/SIMD) while granting the full 256-reg/wave budget.
// ---------------------------------------------------------------------------
__global__ __attribute__((amdgpu_flat_work_group_size(512, 512), amdgpu_waves_per_eu(2)))
void attn_mfma_kernel(
        const unsigned short* __restrict__ qb,
        const unsigned short* __restrict__ kb,
        const unsigned short* __restrict__ vb,
        unsigned short* __restrict__ ob) {
    __shared__ __align__(16) unsigned short Vt[2][2][64][64];  // 32 KB [group][buf][d][key]
    __shared__ __align__(16) float Ep[4][64][64];              // 64 KB epilogue fp32 partials
    __shared__ __align__(16) float Rs[8][2][32];               //  2 KB rowsums [wave][qt][q]

    const int tid  = threadIdx.x;
    const int w    = tid >> 6;        // 0..7
    const int lane = tid & 63;
    const int c32  = lane & 31;
    const int hi   = lane >> 5;
    const int g    = w >> 2;          // key group
    const int kv = blockIdx.y;
    const int h  = kv * 4 + (w & 3);
    const int q0 = blockIdx.x * 64;
    const int s_base = g * 2048;

    // Q B-frags: col=q=c32, k-elems d = kd*16 + hi*8 + j
    bf16x8 qf[2][4];
    {
        const unsigned short* qbase = qb + ((size_t)(q0 + c32) * H + h) * DH + hi * 8;
        #pragma unroll
        for (int qt = 0; qt < 2; ++qt)
            #pragma unroll
            for (int kd = 0; kd < 4; ++kd)
                qf[qt][kd] = *(const bf16x8*)&qbase[qt * 32 * H * DH + kd * 16];
    }

    f32x16 oacc[2][2];    // [qt][dt]: col=d=c32(+32dt), row=q=(r&3)+8(r>>2)+4hi
    #pragma unroll
    for (int qt = 0; qt < 2; ++qt)
        #pragma unroll
        for (int dt = 0; dt < 2; ++dt)
            oacc[qt][dt] = ZERO16;
    float rsum[2] = {0.f, 0.f};   // per-lane partial rowsum, q = qt*32 + c32

    const int tid8 = tid & 255;                 // id within group
    const int sp = tid8 & 31, dc = tid8 >> 5;   // V staging: keys (2sp,2sp+1), d-chunk dc*8

    const unsigned short* kbase = kb + ((size_t)(s_base + c32) * KV + kv) * DH + hi * 8;
    const unsigned short* vbase = vb + ((size_t)(s_base + 2 * sp) * KV + kv) * DH + dc * 8;
    unsigned short* VtW = &Vt[g][0][0][0];      // wave-group V staging base

    // ---- prefetch iter 0 ----
    int4 vreg0 = *(const int4*)&vbase[0];
    int4 vreg1 = *(const int4*)&vbase[KV * DH];
    bf16x8 kf[2][4];   // [key-32-tile][kd]: row=key=c32, k-elems d = kd*16+hi*8+j
    #pragma unroll
    for (int a = 0; a < 2; ++a)
        #pragma unroll
        for (int kd = 0; kd < 4; ++kd)
            kf[a][kd] = *(const bf16x8*)&kbase[a * 32 * KV * DH + kd * 16];

    for (int it = 0; it < 32; ++it) {
        const int bufo = (it & 1) * (64 * 64);   // LDS double-buffer offset (elems)

        // ---- write Vt[g][buf] (pair-transpose via perm, swizzled) ----
        {
            const unsigned* pa = (const unsigned*)&vreg0;
            const unsigned* pb = (const unsigned*)&vreg1;
            #pragma unroll
            for (int t = 0; t < 4; ++t) {
                unsigned lo = __builtin_amdgcn_perm(pb[t], pa[t], 0x05040100u);
                unsigned hv = __builtin_amdgcn_perm(pb[t], pa[t], 0x07060302u);
                int dl = dc * 8 + 2 * t, dh2 = dl + 1;
                *(unsigned*)&VtW[bufo + dl  * 64 + (((sp >> 2) ^ (dl  & 7)) << 3) + 2 * (sp & 3)] = lo;
                *(unsigned*)&VtW[bufo + dh2 * 64 + (((sp >> 2) ^ (dh2 & 7)) << 3) + 2 * (sp & 3)] = hv;
            }
        }
        __syncthreads();   // Vt[g][buf] visible; prior-iter reads complete

        // ---- V prefetch next (overlaps compute) ----
        const int itn = (it + 1) & 31;
        vreg0 = *(const int4*)&vbase[(size_t)itn * 64 * KV * DH];
        vreg1 = *(const int4*)&vbase[(size_t)itn * 64 * KV * DH + KV * DH];

        #pragma unroll
        for (int kt2 = 0; kt2 < 2; ++kt2) {
            bf16x8 pf[2][2];   // [qt][f]: PV A-frags, keys kt2*32 + f*16 + hi*8 + j
            #pragma unroll
            for (int qt = 0; qt < 2; ++qt) {
                // St = K @ Q^T (32x32, K-dim = DH via 4 chained MFMAs)
                f32x16 s = ZERO16;
                #pragma unroll
                for (int kd = 0; kd < 4; ++kd)
                    s = __builtin_amdgcn_mfma_f32_32x32x16_bf16(kf[kt2][kd], qf[qt][kd], s, 0, 0, 0);
                // exp2, truncate to bf16 domain (matches packed PV operand)
                float p[16];
                #pragma unroll
                for (int r = 0; r < 16; ++r)
                    p[r] = __uint_as_float(__float_as_uint(EXP2F(s[r])) & 0xFFFF0000u);
                // rowsum for q = qt*32+c32 over this lane's 16 keys
                float t0 = (p[0] + p[1]) + (p[2] + p[3]);
                float t1 = (p[4] + p[5]) + (p[6] + p[7]);
                float t2 = (p[8] + p[9]) + (p[10] + p[11]);
                float t3 = (p[12] + p[13]) + (p[14] + p[15]);
                rsum[qt] += (t0 + t1) + (t2 + t3);
                // pack key-pairs: u[i] = bf16(p[2i]) | bf16(p[2i+1])<<16
                unsigned u[8];
                #pragma unroll
                for (int i = 0; i < 8; ++i)
                    u[i] = __builtin_amdgcn_perm(__float_as_uint(p[2 * i + 1]),
                                                 __float_as_uint(p[2 * i]), 0x07060302u);
                // cross-half redistribute: swap(u0,u2)->slots{0,2}, swap(u1,u3)->slots{1,3}
                #pragma unroll
                for (int f = 0; f < 2; ++f) {
                    u32x2 e0 = __builtin_amdgcn_permlane32_swap(u[4 * f + 0], u[4 * f + 2], false, false);
                    u32x2 e1 = __builtin_amdgcn_permlane32_swap(u[4 * f + 1], u[4 * f + 3], false, false);
                    pf[qt][f] = mk8(e0.x, e1.x, e0.y, e1.y);
                }
            }
            if (kt2 == 1) {
                // K prefetch next iter (after last St read of kf)
                #pragma unroll
                for (int a = 0; a < 2; ++a)
                    #pragma unroll
                    for (int kd = 0; kd < 4; ++kd)
                        kf[a][kd] = *(const bf16x8*)&kbase[((size_t)itn * 64 + a * 32) * KV * DH + kd * 16];
            }
            // ---- PV half-tile: O += P @ V over keys kt2*32..+31 ----
            __builtin_amdgcn_s_setprio(1);
            #pragma unroll
            for (int dt = 0; dt < 2; ++dt)
                #pragma unroll
                for (int f = 0; f < 2; ++f) {
                    bf16x8 vf = *(const bf16x8*)&VtW[bufo + (dt * 32 + c32) * 64
                                    + ((((kt2 * 4 + f * 2 + hi) ^ (c32 & 7)) << 3))];
                    #pragma unroll
                    for (int qt = 0; qt < 2; ++qt)
                        oacc[qt][dt] = __builtin_amdgcn_mfma_f32_32x32x16_bf16(pf[qt][f], vf, oacc[qt][dt], 0, 0, 0);
                }
            __builtin_amdgcn_s_setprio(0);
        }
    }

    // ---- epilogue: combine hi-halves of rowsums, then key-halves ----
    #pragma unroll
    for (int qt = 0; qt < 2; ++qt) {
        u32x2 e = __builtin_amdgcn_permlane32_swap(__float_as_uint(rsum[qt]),
                                                   __float_as_uint(rsum[qt]), false, false);
        float tot = __uint_as_float(e.x) + __uint_as_float(e.y);
        Rs[w][qt][c32] = tot;   // both hi-lanes write identical value (benign)
    }
    if (g == 1) {
        #pragma unroll
        for (int qt = 0; qt < 2; ++qt)
            #pragma unroll
            for (int dt = 0; dt < 2; ++dt) {
                const int d = dt * 32 + c32;
                #pragma unroll
                for (int rr = 0; rr < 4; ++rr) {
                    const int gq = (qt * 8 + 2 * rr + hi) ^ (d & 15);   // 16B-granule swizzle
                    f32x4 val = {oacc[qt][dt][rr * 4 + 0], oacc[qt][dt][rr * 4 + 1],
                                 oacc[qt][dt][rr * 4 + 2], oacc[qt][dt][rr * 4 + 3]};
                    *(f32x4*)&Ep[w - 4][d][gq * 4] = val;
                }
            }
    }
    __syncthreads();
    if (g == 0) {
        #pragma unroll
        for (int qt = 0; qt < 2; ++qt)
            #pragma unroll
            for (int dt = 0; dt < 2; ++dt) {
                const int d = dt * 32 + c32;
                #pragma unroll
                for (int rr = 0; rr < 4; ++rr) {
                    const int gq = (qt * 8 + 2 * rr + hi) ^ (d & 15);
                    f32x4 val = *(const f32x4*)&Ep[w][d][gq * 4];
                    oacc[qt][dt][rr * 4 + 0] += val[0];
                    oacc[qt][dt][rr * 4 + 1] += val[1];
                    oacc[qt][dt][rr * 4 + 2] += val[2];
                    oacc[qt][dt][rr * 4 + 3] += val[3];
                }
            }
        #pragma unroll
        for (int qt = 0; qt < 2; ++qt)
            #pragma unroll
            for (int rr = 0; rr < 4; ++rr) {
                f32x4 ra = *(const f32x4*)&Rs[w][qt][8 * rr + 4 * hi];
                f32x4 rb = *(const f32x4*)&Rs[w + 4][qt][8 * rr + 4 * hi];
                #pragma unroll
                for (int i = 0; i < 4; ++i) {
                    float inv = 1.0f / (ra[i] + rb[i]);
                    int row = q0 + qt * 32 + 8 * rr + 4 * hi + i;
                    #pragma unroll
                    for (int dt = 0; dt < 2; ++dt)
                        ob[(size_t)row * (H * DH) + h * DH + dt * 32 + c32] =
                            f2bf(oacc[qt][dt][rr * 4 + i] * inv);
                }
            }
    }
}

// ---------------------------------------------------------------------------
extern "C" void kernel_launch(void* const* d_in, const int* in_sizes, int n_in,
                              void* d_out, int out_size, void* d_ws, size_t ws_size,
                              hipStream_t stream) {
    const float* x  = (const float*)d_in[0];
    const float* Wq = (const float*)d_in[1];
    const float* Wk = (const float*)d_in[2];
    const float* Wv = (const float*)d_in[3];
    const float* Wo = (const float*)d_in[4];
    float* out = (float*)d_out;

    // ---- workspace (~26.2 MB) ----
    char* ws = (char*)d_ws;
    unsigned short* xb    = (unsigned short*)ws;                      // 8.39 MB
    unsigned short* ob    = xb;                                       // aliases xb (dead after QKV GEMM)
    unsigned short* qb    = (unsigned short*)(ws + 8388608);          // 8.39 MB
    unsigned short* kb    = (unsigned short*)(ws + 16777216);         // 2.10 MB
    unsigned short* vb    = (unsigned short*)(ws + 18874368);         // 2.10 MB
    unsigned short* WqkvT = (unsigned short*)(ws + 20971520);         // 3.15 MB
    unsigned short* WoT   = (unsigned short*)(ws + 24117248);         // 2.10 MB

    dim3 blk(256);

    // 1) convert + transpose everything
    prep_kernel<<<6656, blk, 0, stream>>>(x, Wq, Wk, Wv, Wo, xb, WqkvT, WoT);

    // 2) fused QKV projection + RoPE + bf16 pack
    gemm_qkv_rope<<<dim3(12, 32), blk, 0, stream>>>(xb, WqkvT, qb, kb, vb);

    // 3) attention (writes bf16 ob over xb — dead)
    attn_mfma_kernel<<<dim3(L / 64, KV), dim3(512), 0, stream>>>(qb, kb, vb, ob);

    // 4) output projection
    gemm_bf16<<<dim3(D / 128, L / 128), blk, 0, stream>>>(ob, WoT, out, L, D, D);
}